// Round 2
// baseline (302.228 us; speedup 1.0000x reference)
//
#include <hip/hip_runtime.h>

#define BATCH 8
#define SEQL 16384
#define NCH 128
#define NH 4
#define HD 32
#define GEPS 1e-5f

typedef __bf16 bf16x8 __attribute__((ext_vector_type(8)));
typedef __bf16 bf16x4 __attribute__((ext_vector_type(4)));
typedef float f32x4 __attribute__((ext_vector_type(4)));

// ---- workspace byte offsets ----
#define WKV_B   0          // 256*128 bf16 = 64 KiB   [o'][c], o' = o-128 (k:0..127, v:128..255)
#define WQ_B    65536      // 128*128 bf16 = 32 KiB   [o][c]
#define WO_B    98304      // 128*128 bf16 = 32 KiB   [o][c]
#define CTXB_B  131072     // 8*4*32*32 bf16 = 64 KiB [b][h][c][d]
#define GNS_B   196608     // 8*2 f32
#define GNF_B   196736     // 8*2 f32
#define CTXP_B  262144     // per-block ctx partials: npart * 4096 f32 (16 KiB each)
                           // followed by Z partials:  npart * 128 f32 (512 B each)

// LDS strides (bf16 units)
// xb: [kblk 4][qc 4][tok 64][ki 8]; qc-stride 520, kblk-stride 2088
// ekv: [ts 2][qt 4][o 256][ti 8]; qt-stride 2056, ts-stride 8232
// pB/attB: [h|ks 4][dq 4][t 64][di 8]; dq-stride 520, h-stride 2088

__global__ void k_prep(const float* __restrict__ wqkv, const float* __restrict__ wout,
                       char* __restrict__ wsb) {
    int i = blockIdx.x * 256 + threadIdx.x;
    __bf16* wkvb = (__bf16*)(wsb + WKV_B);
    __bf16* wqb  = (__bf16*)(wsb + WQ_B);
    __bf16* wob  = (__bf16*)(wsb + WO_B);
    if (i < 384 * 128) {
        int o = i >> 7, c = i & 127;
        __bf16 v = (__bf16)wqkv[i];
        if (o < 128) wqb[o * 128 + c] = v;
        else         wkvb[(o - 128) * 128 + c] = v;
    }
    if (i < 128 * 128) wob[i] = (__bf16)wout[i];
}

// Pass 1: kv = Wkv @ x (MFMA); ek = exp(k); ctx_part = ek (outer) v (MFMA); Z_part = rowsum ek.
// Grid = BATCH * P blocks; each block handles nrep = 256/P chunks of 64 tokens and
// writes ONE private ctx/Z partial slab (plain stores, NO atomics — round-1's 8.4M
// device-scope atomic RMWs were the bottleneck: 33.6 MB of serialized memory-side
// traffic gating block retirement).
__global__ __launch_bounds__(256, 3) void k_pass1(const float* __restrict__ x,
                                                  char* __restrict__ wsb, int P) {
    __shared__ __attribute__((aligned(16))) __bf16 xb[8352];
    __shared__ __attribute__((aligned(16))) __bf16 ekv[16464];
    const int t = threadIdx.x;
    const int lane = t & 63, wave = t >> 6;
    const int n16 = lane & 15, q = lane >> 4;
    const int batch = blockIdx.x / P, sub = blockIdx.x % P;
    const int nrep = 256 / P;
    const __bf16* __restrict__ wkvb = (const __bf16*)(wsb + WKV_B);

    // preload Wkv A-fragments (overlaps the first staging); reused across reps.
    bf16x8 aw[4][4];
#pragma unroll
    for (int mt = 0; mt < 4; mt++)
#pragma unroll
        for (int ks = 0; ks < 4; ks++)
            aw[mt][ks] = *(const bf16x8*)&wkvb[(wave * 64 + mt * 16 + n16) * 128 + ks * 32 + q * 8];

    f32x4 ctxacc[2][2];
#pragma unroll
    for (int i = 0; i < 2; i++)
#pragma unroll
        for (int j = 0; j < 2; j++) ctxacc[i][j] = (f32x4){0.f, 0.f, 0.f, 0.f};
    float zacc[4][4];
#pragma unroll
    for (int i = 0; i < 4; i++)
#pragma unroll
        for (int j = 0; j < 4; j++) zacc[i][j] = 0.f;

    for (int rep = 0; rep < nrep; rep++) {
        const int chunk = sub + rep * P;
        const float* xg = x + (size_t)(batch * SEQL + chunk * 64) * NCH;
        // stage x -> bf16 LDS in B-operand layout
#pragma unroll
        for (int r = 0; r < 8; r++) {
            int e = t + r * 256;
            int tok = e >> 5, c4 = (e & 31) * 4;
            float4 v = ((const float4*)xg)[e];
            bf16x4 h; h.x = (__bf16)v.x; h.y = (__bf16)v.y; h.z = (__bf16)v.z; h.w = (__bf16)v.w;
            *(bf16x4*)&xb[(c4 >> 5) * 2088 + ((c4 >> 3) & 3) * 520 + tok * 8 + (c4 & 7)] = h;
        }
        __syncthreads();

        // KV GEMM in two token-halves to cap live accumulators (VGPR):
#pragma unroll
        for (int half = 0; half < 2; half++) {
            f32x4 kvacc[4][2];
#pragma unroll
            for (int i = 0; i < 4; i++)
#pragma unroll
                for (int j = 0; j < 2; j++) kvacc[i][j] = (f32x4){0.f, 0.f, 0.f, 0.f};
#pragma unroll
            for (int ks = 0; ks < 4; ks++) {
                bf16x8 b[2];
#pragma unroll
                for (int nl = 0; nl < 2; nl++)
                    b[nl] = *(const bf16x8*)&xb[ks * 2088 + q * 520 + ((half * 2 + nl) * 16 + n16) * 8];
#pragma unroll
                for (int mt = 0; mt < 4; mt++)
#pragma unroll
                    for (int nl = 0; nl < 2; nl++)
                        kvacc[mt][nl] = __builtin_amdgcn_mfma_f32_16x16x32_bf16(
                            aw[mt][ks], b[nl], kvacc[mt][nl], 0, 0, 0);
            }
            // exp (k-waves), accumulate Z, write ekv LDS in frag-friendly layout
#pragma unroll
            for (int mt = 0; mt < 4; mt++)
#pragma unroll
                for (int nl = 0; nl < 2; nl++) {
                    int tt = (half * 2 + nl) * 16 + n16;
                    int base = (tt >> 5) * 8232 + ((tt >> 3) & 3) * 2056 + (tt & 7);
#pragma unroll
                    for (int r = 0; r < 4; r++) {
                        float vv = kvacc[mt][nl][r];
                        if (wave < 2) { vv = __expf(vv); zacc[mt][r] += vv; }
                        int o = wave * 64 + mt * 16 + q * 4 + r;
                        ekv[base + o * 8] = (__bf16)vv;
                    }
                }
        }
        __syncthreads();

        // ctx MFMA: wave = head h; A = ek[c][t] (c = h*32..), B = v[d][t]
#pragma unroll
        for (int ks2 = 0; ks2 < 2; ks2++) {
            bf16x8 ea[2], vb[2];
#pragma unroll
            for (int ml = 0; ml < 2; ml++) {
                ea[ml] = *(const bf16x8*)&ekv[ks2 * 8232 + q * 2056 + (wave * 32 + ml * 16 + n16) * 8];
                vb[ml] = *(const bf16x8*)&ekv[ks2 * 8232 + q * 2056 + (128 + wave * 32 + ml * 16 + n16) * 8];
            }
#pragma unroll
            for (int ml = 0; ml < 2; ml++)
#pragma unroll
                for (int nl = 0; nl < 2; nl++)
                    ctxacc[ml][nl] = __builtin_amdgcn_mfma_f32_16x16x32_bf16(
                        ea[ml], vb[nl], ctxacc[ml][nl], 0, 0, 0);
        }
        __syncthreads();
    }

    // write private ctx partial (plain stores): slab layout [h][c][d]
    float* ctxp = (float*)(wsb + CTXP_B) + (size_t)blockIdx.x * 4096 + wave * 1024;
#pragma unroll
    for (int ml = 0; ml < 2; ml++)
#pragma unroll
        for (int nl = 0; nl < 2; nl++)
#pragma unroll
            for (int r = 0; r < 4; r++)
                ctxp[(ml * 16 + q * 4 + r) * 32 + nl * 16 + n16] = ctxacc[ml][nl][r];
    // Z partial: sum over tokens = butterfly over n16 lanes, lane0 stores
    if (wave < 2) {
        float* zp = (float*)(wsb + CTXP_B) + (size_t)gridDim.x * 4096 + (size_t)blockIdx.x * 128;
#pragma unroll
        for (int mt = 0; mt < 4; mt++)
#pragma unroll
            for (int r = 0; r < 4; r++) {
                float z = zacc[mt][r];
                z += __shfl_xor(z, 1); z += __shfl_xor(z, 2);
                z += __shfl_xor(z, 4); z += __shfl_xor(z, 8);
                if (n16 == 0) zp[wave * 64 + mt * 16 + q * 4 + r] = z;
            }
    }
}

// Reduce partials and normalize: ctxb[b][h][c][d] = (sum_p ctxp) / (sum_p zp[h*32+c])
__global__ __launch_bounds__(256) void k_reduce(char* __restrict__ wsb, int P) {
    int i = blockIdx.x * 256 + threadIdx.x;      // grid 128 -> i < 32768
    int b = i >> 12, elem = i & 4095;
    int hc = elem >> 5;                          // h*32 + c
    const float* ctxp = (const float*)(wsb + CTXP_B);
    const float* zp = ctxp + (size_t)(BATCH * P) * 4096;
    float cs = 0.f, zs = 0.f;
    for (int p = 0; p < P; p++) {
        size_t slab = (size_t)(b * P + p);
        cs += ctxp[slab * 4096 + elem];
        zs += zp[slab * 128 + hc];
    }
    __bf16* ctxb = (__bf16*)(wsb + CTXB_B);
    ctxb[i] = (__bf16)(cs / zs);
}

// Pass 2: q = Wq @ x (MFMA); softmax over head-dim in registers; attn = ctx @ p (MFMA);
// out = Wout @ attn + bias (MFMA); GN partial sums; store pre-GN out.
// One 64-token chunk per block (grid 2048). attB aliases xb (xb dead after the
// pB barrier) -> LDS 33.4 KiB -> 4 blocks/CU. Weights loaded inline per-ks.
__global__ __launch_bounds__(256, 4) void k_pass2(const float* __restrict__ x,
                                                  const float* __restrict__ bout,
                                                  char* __restrict__ wsb,
                                                  float* __restrict__ out) {
    __shared__ __attribute__((aligned(16))) __bf16 xb[8352];   // reused as attB
    __shared__ __attribute__((aligned(16))) __bf16 pB[8352];
    __shared__ float gred[8];
    const int t = threadIdx.x;
    const int lane = t & 63, wave = t >> 6;       // wave == head h
    const int n16 = lane & 15, q = lane >> 4;
    const int batch = blockIdx.x >> 8, chunk = blockIdx.x & 255;
    const __bf16* __restrict__ wqb = (const __bf16*)(wsb + WQ_B);
    const __bf16* __restrict__ wob = (const __bf16*)(wsb + WO_B);
    const __bf16* __restrict__ ctxb = (const __bf16*)(wsb + CTXB_B);

    const size_t tok0 = (size_t)batch * SEQL + chunk * 64;
    const float* xg = x + tok0 * NCH;
#pragma unroll
    for (int r = 0; r < 8; r++) {
        int e = t + r * 256;
        int tok = e >> 5, c4 = (e & 31) * 4;
        float4 v = ((const float4*)xg)[e];
        bf16x4 h; h.x = (__bf16)v.x; h.y = (__bf16)v.y; h.z = (__bf16)v.z; h.w = (__bf16)v.w;
        *(bf16x4*)&xb[(c4 >> 5) * 2088 + ((c4 >> 3) & 3) * 520 + tok * 8 + (c4 & 7)] = h;
    }
    __syncthreads();

    // Wq GEMM: wave handles head's 32 q-channels (mtiles 2h, 2h+1)
    f32x4 qacc[2][4];
#pragma unroll
    for (int i = 0; i < 2; i++)
#pragma unroll
        for (int j = 0; j < 4; j++) qacc[i][j] = (f32x4){0.f, 0.f, 0.f, 0.f};
#pragma unroll
    for (int ks = 0; ks < 4; ks++) {
        bf16x8 aq_k[2];
#pragma unroll
        for (int ml = 0; ml < 2; ml++)
            aq_k[ml] = *(const bf16x8*)&wqb[(wave * 32 + ml * 16 + n16) * 128 + ks * 32 + q * 8];
        bf16x8 b[4];
#pragma unroll
        for (int nt = 0; nt < 4; nt++)
            b[nt] = *(const bf16x8*)&xb[ks * 2088 + q * 520 + (nt * 16 + n16) * 8];
#pragma unroll
        for (int ml = 0; ml < 2; ml++)
#pragma unroll
            for (int nt = 0; nt < 4; nt++)
                qacc[ml][nt] = __builtin_amdgcn_mfma_f32_16x16x32_bf16(
                    aq_k[ml], b[nt], qacc[ml][nt], 0, 0, 0);
    }
    // softmax over the 32 head channels, entirely in registers + 2 shuffles
#pragma unroll
    for (int nt = 0; nt < 4; nt++) {
        float ss = 0.f;
#pragma unroll
        for (int ml = 0; ml < 2; ml++)
#pragma unroll
            for (int r = 0; r < 4; r++) {
                float e = __expf(qacc[ml][nt][r]);
                qacc[ml][nt][r] = e;
                ss += e;
            }
        ss += __shfl_xor(ss, 16);
        ss += __shfl_xor(ss, 32);
        float inv = 0.17677669529663687f / ss;   // (1/sqrt(32)) / denom
#pragma unroll
        for (int ml = 0; ml < 2; ml++)
#pragma unroll
            for (int r = 0; r < 4; r++) qacc[ml][nt][r] *= inv;
    }
    // write p to LDS: p[d = ml*16+q*4+r][t], layout [h][d>>3][t][d&7]
#pragma unroll
    for (int ml = 0; ml < 2; ml++)
#pragma unroll
        for (int nt = 0; nt < 4; nt++) {
            bf16x4 h;
            h.x = (__bf16)qacc[ml][nt][0]; h.y = (__bf16)qacc[ml][nt][1];
            h.z = (__bf16)qacc[ml][nt][2]; h.w = (__bf16)qacc[ml][nt][3];
            *(bf16x4*)&pB[wave * 2088 + (ml * 2 + (q >> 1)) * 520 +
                          (nt * 16 + n16) * 8 + (q & 1) * 4] = h;
        }
    __syncthreads();
    // attn MFMA: A = ctx[h] (32c x 32d), B = p[h] (32d x 64t)
    bf16x8 actx[2];
#pragma unroll
    for (int ml = 0; ml < 2; ml++)
        actx[ml] = *(const bf16x8*)&ctxb[((size_t)(batch * 4 + wave) * 32 + ml * 16 + n16) * 32 + q * 8];
    f32x4 aacc[2][4];
#pragma unroll
    for (int ml = 0; ml < 2; ml++)
#pragma unroll
        for (int nt = 0; nt < 4; nt++) {
            bf16x8 pb = *(const bf16x8*)&pB[wave * 2088 + q * 520 + (nt * 16 + n16) * 8];
            aacc[ml][nt] = __builtin_amdgcn_mfma_f32_16x16x32_bf16(
                actx[ml], pb, (f32x4){0.f, 0.f, 0.f, 0.f}, 0, 0, 0);
        }
    // write attn to LDS (attB == xb; safe: all xb reads finished before pB barrier):
    // c_in = h*32 + ml*16 + q*4 + r, layout [c>>5][ (c>>3)&3 ][t][c&7]
    __bf16* attB = xb;
#pragma unroll
    for (int ml = 0; ml < 2; ml++)
#pragma unroll
        for (int nt = 0; nt < 4; nt++) {
            bf16x4 h;
            h.x = (__bf16)aacc[ml][nt][0]; h.y = (__bf16)aacc[ml][nt][1];
            h.z = (__bf16)aacc[ml][nt][2]; h.w = (__bf16)aacc[ml][nt][3];
            *(bf16x4*)&attB[wave * 2088 + (ml * 2 + (q >> 1)) * 520 +
                            (nt * 16 + n16) * 8 + (q & 1) * 4] = h;
        }
    __syncthreads();
    // Wout GEMM: wave covers out channels o = wave*32 + ml*16 + ...
    f32x4 oacc[2][4];
#pragma unroll
    for (int i = 0; i < 2; i++)
#pragma unroll
        for (int j = 0; j < 4; j++) oacc[i][j] = (f32x4){0.f, 0.f, 0.f, 0.f};
#pragma unroll
    for (int ks = 0; ks < 4; ks++) {
        bf16x8 ao_k[2];
#pragma unroll
        for (int ml = 0; ml < 2; ml++)
            ao_k[ml] = *(const bf16x8*)&wob[(wave * 32 + ml * 16 + n16) * 128 + ks * 32 + q * 8];
        bf16x8 b[4];
#pragma unroll
        for (int nt = 0; nt < 4; nt++)
            b[nt] = *(const bf16x8*)&attB[ks * 2088 + q * 520 + (nt * 16 + n16) * 8];
#pragma unroll
        for (int ml = 0; ml < 2; ml++)
#pragma unroll
            for (int nt = 0; nt < 4; nt++)
                oacc[ml][nt] = __builtin_amdgcn_mfma_f32_16x16x32_bf16(
                    ao_k[ml], b[nt], oacc[ml][nt], 0, 0, 0);
    }
    // epilogue: bias, GN sums, store
    float4 bias[2];
#pragma unroll
    for (int ml = 0; ml < 2; ml++)
        bias[ml] = *(const float4*)&bout[wave * 32 + ml * 16 + q * 4];
    float s1 = 0.f, s2 = 0.f;
#pragma unroll
    for (int ml = 0; ml < 2; ml++)
#pragma unroll
        for (int nt = 0; nt < 4; nt++) {
            float4 vv;
            vv.x = oacc[ml][nt][0] + bias[ml].x;
            vv.y = oacc[ml][nt][1] + bias[ml].y;
            vv.z = oacc[ml][nt][2] + bias[ml].z;
            vv.w = oacc[ml][nt][3] + bias[ml].w;
            s1 += vv.x + vv.y + vv.z + vv.w;
            s2 += vv.x * vv.x + vv.y * vv.y + vv.z * vv.z + vv.w * vv.w;
            *(float4*)&out[(tok0 + nt * 16 + n16) * NCH + wave * 32 + ml * 16 + q * 4] = vv;
        }
    // block-level GN reduction -> 2 atomics per block
#pragma unroll
    for (int off = 32; off > 0; off >>= 1) {
        s1 += __shfl_xor(s1, off);
        s2 += __shfl_xor(s2, off);
    }
    if (lane == 0) { gred[wave * 2 + 0] = s1; gred[wave * 2 + 1] = s2; }
    __syncthreads();
    if (t < 2) {
        float s = gred[t] + gred[2 + t] + gred[4 + t] + gred[6 + t];
        atomicAdd(&((float*)(wsb + GNS_B))[batch * 2 + t], s);
    }
}

__global__ void k_gnfinal(char* __restrict__ wsb) {
    int b = threadIdx.x;
    if (b < BATCH) {
        const float n = (float)NCH * (float)SEQL;
        const float* gns = (const float*)(wsb + GNS_B);
        float* gnf = (float*)(wsb + GNF_B);
        float mean = gns[b * 2] / n;
        float var = gns[b * 2 + 1] / n - mean * mean;
        gnf[b * 2] = mean;
        gnf[b * 2 + 1] = rsqrtf(var + GEPS);
    }
}

__global__ __launch_bounds__(256) void k_gnorm(float* __restrict__ out,
                                               const char* __restrict__ wsb,
                                               const float* __restrict__ gw,
                                               const float* __restrict__ gb) {
    size_t i4 = (size_t)blockIdx.x * 256 + threadIdx.x;
    int b = (int)(i4 >> 19);
    int c4 = (int)(i4 & 31);
    const float* gnf = (const float*)(wsb + GNF_B);
    float mean = gnf[b * 2], rstd = gnf[b * 2 + 1];
    float4 w = *(const float4*)&gw[c4 * 4];
    float4 bb = *(const float4*)&gb[c4 * 4];
    float4 v = ((float4*)out)[i4];
    v.x = (v.x - mean) * rstd * w.x + bb.x;
    v.y = (v.y - mean) * rstd * w.y + bb.y;
    v.z = (v.z - mean) * rstd * w.z + bb.z;
    v.w = (v.w - mean) * rstd * w.w + bb.w;
    ((float4*)out)[i4] = v;
}

extern "C" void kernel_launch(void* const* d_in, const int* in_sizes, int n_in,
                              void* d_out, int out_size, void* d_ws, size_t ws_size,
                              hipStream_t stream) {
    const float* x    = (const float*)d_in[0];
    const float* wqkv = (const float*)d_in[1];
    const float* wout = (const float*)d_in[2];
    const float* bout = (const float*)d_in[3];
    const float* gw   = (const float*)d_in[4];
    const float* gb   = (const float*)d_in[5];
    float* out = (float*)d_out;
    char* wsb  = (char*)d_ws;

    // pick partial count to fit workspace: P partials/batch, each 16 KiB ctx + 512 B Z
    int P = 256;
    while (P > 1 &&
           (size_t)CTXP_B + (size_t)BATCH * P * (16384 + 512) > ws_size)
        P >>= 1;

    hipMemsetAsync(wsb + GNS_B, 0, 64, stream);
    k_prep<<<192, 256, 0, stream>>>(wqkv, wout, wsb);
    k_pass1<<<BATCH * P, 256, 0, stream>>>(x, wsb, P);
    k_reduce<<<128, 256, 0, stream>>>(wsb, P);
    k_pass2<<<2048, 256, 0, stream>>>(x, bout, wsb, out);
    k_gnfinal<<<1, 64, 0, stream>>>(wsb);
    k_gnorm<<<16384, 256, 0, stream>>>(out, wsb, gw, gb);
}

// Round 3
// 253.089 us; speedup vs baseline: 1.1942x; 1.1942x over previous
//
#include <hip/hip_runtime.h>

#define BATCH 8
#define SEQL 16384
#define NCH 128
#define NH 4
#define HD 32
#define GEPS 1e-5f

typedef __bf16 bf16x8 __attribute__((ext_vector_type(8)));
typedef __bf16 bf16x4 __attribute__((ext_vector_type(4)));
typedef float f32x4 __attribute__((ext_vector_type(4)));

// ---- workspace byte offsets ----
#define WKV_B   0          // 256*128 bf16 = 64 KiB   [o'][c], o' = o-128 (k:0..127, v:128..255)
#define WQ_B    65536      // 128*128 bf16 = 32 KiB   [o][c]
#define WO_B    98304      // 128*128 bf16 = 32 KiB   [o][c]
#define CTXB_B  131072     // 8*4*32*32 bf16 = 64 KiB [b][h][c][d]
#define GNS_B   196608     // 8*2 f32
#define CTXP_B  262144     // ctx partials [b*P + p][4096] f32, then zT [b*128+hc][P] f32

// LDS strides (bf16 units)
// xb: [kblk 4][qc 4][tok 64][ki 8]; qc-stride 520, kblk-stride 2088
// ekv: [ts 2][qt 4][o 256][ti 8]; qt-stride 2056, ts-stride 8232
// pB/attB: [h|ks 4][dq 4][t 64][di 8]; dq-stride 520, h-stride 2088

__global__ void k_prep(const float* __restrict__ wqkv, const float* __restrict__ wout,
                       char* __restrict__ wsb) {
    int i = blockIdx.x * 256 + threadIdx.x;
    __bf16* wkvb = (__bf16*)(wsb + WKV_B);
    __bf16* wqb  = (__bf16*)(wsb + WQ_B);
    __bf16* wob  = (__bf16*)(wsb + WO_B);
    if (i < 384 * 128) {
        int o = i >> 7, c = i & 127;
        __bf16 v = (__bf16)wqkv[i];
        if (o < 128) wqb[o * 128 + c] = v;
        else         wkvb[(o - 128) * 128 + c] = v;
    }
    if (i < 128 * 128) wob[i] = (__bf16)wout[i];
    if (i < 16) ((float*)(wsb + GNS_B))[i] = 0.f;   // zero GN accumulators
}

// Pass 1: kv = Wkv @ x (MFMA); ek = exp(k); ctx_part = ek (outer) v (MFMA); Z_part = rowsum ek.
// Grid = BATCH * P; each block writes ONE private ctx partial slab (plain stores, no
// atomics) and a TRANSPOSED Z partial (zT[hc][p]) so k_reduce's Z sum is contiguous.
__global__ __launch_bounds__(256, 3) void k_pass1(const float* __restrict__ x,
                                                  char* __restrict__ wsb, int P) {
    __shared__ __attribute__((aligned(16))) __bf16 xb[8352];
    __shared__ __attribute__((aligned(16))) __bf16 ekv[16464];
    const int t = threadIdx.x;
    const int lane = t & 63, wave = t >> 6;
    const int n16 = lane & 15, q = lane >> 4;
    const int batch = blockIdx.x / P, sub = blockIdx.x % P;
    const int nrep = 256 / P;
    const __bf16* __restrict__ wkvb = (const __bf16*)(wsb + WKV_B);

    bf16x8 aw[4][4];
#pragma unroll
    for (int mt = 0; mt < 4; mt++)
#pragma unroll
        for (int ks = 0; ks < 4; ks++)
            aw[mt][ks] = *(const bf16x8*)&wkvb[(wave * 64 + mt * 16 + n16) * 128 + ks * 32 + q * 8];

    f32x4 ctxacc[2][2];
#pragma unroll
    for (int i = 0; i < 2; i++)
#pragma unroll
        for (int j = 0; j < 2; j++) ctxacc[i][j] = (f32x4){0.f, 0.f, 0.f, 0.f};
    float zacc[4][4];
#pragma unroll
    for (int i = 0; i < 4; i++)
#pragma unroll
        for (int j = 0; j < 4; j++) zacc[i][j] = 0.f;

    for (int rep = 0; rep < nrep; rep++) {
        const int chunk = sub + rep * P;
        const float* xg = x + (size_t)(batch * SEQL + chunk * 64) * NCH;
#pragma unroll
        for (int r = 0; r < 8; r++) {
            int e = t + r * 256;
            int tok = e >> 5, c4 = (e & 31) * 4;
            float4 v = ((const float4*)xg)[e];
            bf16x4 h; h.x = (__bf16)v.x; h.y = (__bf16)v.y; h.z = (__bf16)v.z; h.w = (__bf16)v.w;
            *(bf16x4*)&xb[(c4 >> 5) * 2088 + ((c4 >> 3) & 3) * 520 + tok * 8 + (c4 & 7)] = h;
        }
        __syncthreads();

#pragma unroll
        for (int half = 0; half < 2; half++) {
            f32x4 kvacc[4][2];
#pragma unroll
            for (int i = 0; i < 4; i++)
#pragma unroll
                for (int j = 0; j < 2; j++) kvacc[i][j] = (f32x4){0.f, 0.f, 0.f, 0.f};
#pragma unroll
            for (int ks = 0; ks < 4; ks++) {
                bf16x8 b[2];
#pragma unroll
                for (int nl = 0; nl < 2; nl++)
                    b[nl] = *(const bf16x8*)&xb[ks * 2088 + q * 520 + ((half * 2 + nl) * 16 + n16) * 8];
#pragma unroll
                for (int mt = 0; mt < 4; mt++)
#pragma unroll
                    for (int nl = 0; nl < 2; nl++)
                        kvacc[mt][nl] = __builtin_amdgcn_mfma_f32_16x16x32_bf16(
                            aw[mt][ks], b[nl], kvacc[mt][nl], 0, 0, 0);
            }
#pragma unroll
            for (int mt = 0; mt < 4; mt++)
#pragma unroll
                for (int nl = 0; nl < 2; nl++) {
                    int tt = (half * 2 + nl) * 16 + n16;
                    int base = (tt >> 5) * 8232 + ((tt >> 3) & 3) * 2056 + (tt & 7);
#pragma unroll
                    for (int r = 0; r < 4; r++) {
                        float vv = kvacc[mt][nl][r];
                        if (wave < 2) { vv = __expf(vv); zacc[mt][r] += vv; }
                        int o = wave * 64 + mt * 16 + q * 4 + r;
                        ekv[base + o * 8] = (__bf16)vv;
                    }
                }
        }
        __syncthreads();

#pragma unroll
        for (int ks2 = 0; ks2 < 2; ks2++) {
            bf16x8 ea[2], vb[2];
#pragma unroll
            for (int ml = 0; ml < 2; ml++) {
                ea[ml] = *(const bf16x8*)&ekv[ks2 * 8232 + q * 2056 + (wave * 32 + ml * 16 + n16) * 8];
                vb[ml] = *(const bf16x8*)&ekv[ks2 * 8232 + q * 2056 + (128 + wave * 32 + ml * 16 + n16) * 8];
            }
#pragma unroll
            for (int ml = 0; ml < 2; ml++)
#pragma unroll
                for (int nl = 0; nl < 2; nl++)
                    ctxacc[ml][nl] = __builtin_amdgcn_mfma_f32_16x16x32_bf16(
                        ea[ml], vb[nl], ctxacc[ml][nl], 0, 0, 0);
        }
        __syncthreads();
    }

    // private ctx partial, plain stores: slab layout [h][c][d]
    float* ctxp = (float*)(wsb + CTXP_B) + (size_t)blockIdx.x * 4096 + wave * 1024;
#pragma unroll
    for (int ml = 0; ml < 2; ml++)
#pragma unroll
        for (int nl = 0; nl < 2; nl++)
#pragma unroll
            for (int r = 0; r < 4; r++)
                ctxp[(ml * 16 + q * 4 + r) * 32 + nl * 16 + n16] = ctxacc[ml][nl][r];
    // transposed Z partial: zT[b*128 + o][p]
    if (wave < 2) {
        float* zpT = (float*)(wsb + CTXP_B) + (size_t)BATCH * P * 4096;
#pragma unroll
        for (int mt = 0; mt < 4; mt++)
#pragma unroll
            for (int r = 0; r < 4; r++) {
                float z = zacc[mt][r];
                z += __shfl_xor(z, 1); z += __shfl_xor(z, 2);
                z += __shfl_xor(z, 4); z += __shfl_xor(z, 8);
                if (n16 == 0)
                    zpT[((size_t)batch * 128 + wave * 64 + mt * 16 + q * 4 + r) * P + sub] = z;
            }
    }
}

// Parallel reduce + normalize: grid = BATCH*64 blocks; block = 64 elems x 4 p-groups.
// Coalesced 256B bursts per wave; Z summed by 128-thread butterfly on the transposed
// layout. Round-2's serial version (128 blocks, 256-deep strided walk) was 72us @ 264GB/s.
__global__ __launch_bounds__(256) void k_reduce(char* __restrict__ wsb, int P) {
    __shared__ float red[4][64];
    __shared__ float zw[4];
    const int tid = threadIdx.x;
    const int b = blockIdx.x >> 6, eg = blockIdx.x & 63;
    const int elemBase = eg * 64;
    const float* ctxp = (const float*)(wsb + CTXP_B);
    const float* zpT = ctxp + (size_t)BATCH * P * 4096;

    // Z sums for this block's 2 hc values (hc = eg*2 + hc2)
    {
        int hc2 = tid >> 7, pslot = tid & 127;
        float zs = 0.f;
        for (int p = pslot; p < P; p += 128)
            zs += zpT[((size_t)b * 128 + eg * 2 + hc2) * P + p];
#pragma unroll
        for (int off = 32; off > 0; off >>= 1) zs += __shfl_xor(zs, off);
        if ((tid & 63) == 0) zw[tid >> 6] = zs;
    }
    // ctx partial sums: thread (pg, e) sums P/4 slabs, coalesced across e
    {
        int pg = tid >> 6, e = tid & 63;
        int cnt = P >> 2;
        const float* base = ctxp + ((size_t)(b * P + pg * cnt)) * 4096 + elemBase + e;
        float cs = 0.f;
        for (int k = 0; k < cnt; k++) cs += base[(size_t)k * 4096];
        red[pg][e] = cs;
    }
    __syncthreads();
    if (tid < 64) {
        float tot = red[0][tid] + red[1][tid] + red[2][tid] + red[3][tid];
        float zs = zw[(tid >> 5) * 2] + zw[(tid >> 5) * 2 + 1];
        ((__bf16*)(wsb + CTXB_B))[(size_t)b * 4096 + elemBase + tid] = (__bf16)(tot / zs);
    }
}

// Pass 2: q = Wq @ x (MFMA); softmax over head-dim in registers; attn = ctx @ p (MFMA);
// out = Wout @ attn + bias (MFMA); GN partial sums; store pre-GN out.
__global__ __launch_bounds__(256, 4) void k_pass2(const float* __restrict__ x,
                                                  const float* __restrict__ bout,
                                                  char* __restrict__ wsb,
                                                  float* __restrict__ out) {
    __shared__ __attribute__((aligned(16))) __bf16 xb[8352];   // reused as attB
    __shared__ __attribute__((aligned(16))) __bf16 pB[8352];
    __shared__ float gred[8];
    const int t = threadIdx.x;
    const int lane = t & 63, wave = t >> 6;       // wave == head h
    const int n16 = lane & 15, q = lane >> 4;
    const int batch = blockIdx.x >> 8, chunk = blockIdx.x & 255;
    const __bf16* __restrict__ wqb = (const __bf16*)(wsb + WQ_B);
    const __bf16* __restrict__ wob = (const __bf16*)(wsb + WO_B);
    const __bf16* __restrict__ ctxb = (const __bf16*)(wsb + CTXB_B);

    const size_t tok0 = (size_t)batch * SEQL + chunk * 64;
    const float* xg = x + tok0 * NCH;
#pragma unroll
    for (int r = 0; r < 8; r++) {
        int e = t + r * 256;
        int tok = e >> 5, c4 = (e & 31) * 4;
        float4 v = ((const float4*)xg)[e];
        bf16x4 h; h.x = (__bf16)v.x; h.y = (__bf16)v.y; h.z = (__bf16)v.z; h.w = (__bf16)v.w;
        *(bf16x4*)&xb[(c4 >> 5) * 2088 + ((c4 >> 3) & 3) * 520 + tok * 8 + (c4 & 7)] = h;
    }
    __syncthreads();

    f32x4 qacc[2][4];
#pragma unroll
    for (int i = 0; i < 2; i++)
#pragma unroll
        for (int j = 0; j < 4; j++) qacc[i][j] = (f32x4){0.f, 0.f, 0.f, 0.f};
#pragma unroll
    for (int ks = 0; ks < 4; ks++) {
        bf16x8 aq_k[2];
#pragma unroll
        for (int ml = 0; ml < 2; ml++)
            aq_k[ml] = *(const bf16x8*)&wqb[(wave * 32 + ml * 16 + n16) * 128 + ks * 32 + q * 8];
        bf16x8 b[4];
#pragma unroll
        for (int nt = 0; nt < 4; nt++)
            b[nt] = *(const bf16x8*)&xb[ks * 2088 + q * 520 + (nt * 16 + n16) * 8];
#pragma unroll
        for (int ml = 0; ml < 2; ml++)
#pragma unroll
            for (int nt = 0; nt < 4; nt++)
                qacc[ml][nt] = __builtin_amdgcn_mfma_f32_16x16x32_bf16(
                    aq_k[ml], b[nt], qacc[ml][nt], 0, 0, 0);
    }
#pragma unroll
    for (int nt = 0; nt < 4; nt++) {
        float ss = 0.f;
#pragma unroll
        for (int ml = 0; ml < 2; ml++)
#pragma unroll
            for (int r = 0; r < 4; r++) {
                float e = __expf(qacc[ml][nt][r]);
                qacc[ml][nt][r] = e;
                ss += e;
            }
        ss += __shfl_xor(ss, 16);
        ss += __shfl_xor(ss, 32);
        float inv = 0.17677669529663687f / ss;   // (1/sqrt(32)) / denom
#pragma unroll
        for (int ml = 0; ml < 2; ml++)
#pragma unroll
            for (int r = 0; r < 4; r++) qacc[ml][nt][r] *= inv;
    }
#pragma unroll
    for (int ml = 0; ml < 2; ml++)
#pragma unroll
        for (int nt = 0; nt < 4; nt++) {
            bf16x4 h;
            h.x = (__bf16)qacc[ml][nt][0]; h.y = (__bf16)qacc[ml][nt][1];
            h.z = (__bf16)qacc[ml][nt][2]; h.w = (__bf16)qacc[ml][nt][3];
            *(bf16x4*)&pB[wave * 2088 + (ml * 2 + (q >> 1)) * 520 +
                          (nt * 16 + n16) * 8 + (q & 1) * 4] = h;
        }
    __syncthreads();
    bf16x8 actx[2];
#pragma unroll
    for (int ml = 0; ml < 2; ml++)
        actx[ml] = *(const bf16x8*)&ctxb[((size_t)(batch * 4 + wave) * 32 + ml * 16 + n16) * 32 + q * 8];
    f32x4 aacc[2][4];
#pragma unroll
    for (int ml = 0; ml < 2; ml++)
#pragma unroll
        for (int nt = 0; nt < 4; nt++) {
            bf16x8 pb = *(const bf16x8*)&pB[wave * 2088 + q * 520 + (nt * 16 + n16) * 8];
            aacc[ml][nt] = __builtin_amdgcn_mfma_f32_16x16x32_bf16(
                actx[ml], pb, (f32x4){0.f, 0.f, 0.f, 0.f}, 0, 0, 0);
        }
    __bf16* attB = xb;
#pragma unroll
    for (int ml = 0; ml < 2; ml++)
#pragma unroll
        for (int nt = 0; nt < 4; nt++) {
            bf16x4 h;
            h.x = (__bf16)aacc[ml][nt][0]; h.y = (__bf16)aacc[ml][nt][1];
            h.z = (__bf16)aacc[ml][nt][2]; h.w = (__bf16)aacc[ml][nt][3];
            *(bf16x4*)&attB[wave * 2088 + (ml * 2 + (q >> 1)) * 520 +
                            (nt * 16 + n16) * 8 + (q & 1) * 4] = h;
        }
    __syncthreads();
    f32x4 oacc[2][4];
#pragma unroll
    for (int i = 0; i < 2; i++)
#pragma unroll
        for (int j = 0; j < 4; j++) oacc[i][j] = (f32x4){0.f, 0.f, 0.f, 0.f};
#pragma unroll
    for (int ks = 0; ks < 4; ks++) {
        bf16x8 ao_k[2];
#pragma unroll
        for (int ml = 0; ml < 2; ml++)
            ao_k[ml] = *(const bf16x8*)&wob[(wave * 32 + ml * 16 + n16) * 128 + ks * 32 + q * 8];
        bf16x8 b[4];
#pragma unroll
        for (int nt = 0; nt < 4; nt++)
            b[nt] = *(const bf16x8*)&attB[ks * 2088 + q * 520 + (nt * 16 + n16) * 8];
#pragma unroll
        for (int ml = 0; ml < 2; ml++)
#pragma unroll
            for (int nt = 0; nt < 4; nt++)
                oacc[ml][nt] = __builtin_amdgcn_mfma_f32_16x16x32_bf16(
                    ao_k[ml], b[nt], oacc[ml][nt], 0, 0, 0);
    }
    float4 bias[2];
#pragma unroll
    for (int ml = 0; ml < 2; ml++)
        bias[ml] = *(const float4*)&bout[wave * 32 + ml * 16 + q * 4];
    float s1 = 0.f, s2 = 0.f;
#pragma unroll
    for (int ml = 0; ml < 2; ml++)
#pragma unroll
        for (int nt = 0; nt < 4; nt++) {
            float4 vv;
            vv.x = oacc[ml][nt][0] + bias[ml].x;
            vv.y = oacc[ml][nt][1] + bias[ml].y;
            vv.z = oacc[ml][nt][2] + bias[ml].z;
            vv.w = oacc[ml][nt][3] + bias[ml].w;
            s1 += vv.x + vv.y + vv.z + vv.w;
            s2 += vv.x * vv.x + vv.y * vv.y + vv.z * vv.z + vv.w * vv.w;
            *(float4*)&out[(tok0 + nt * 16 + n16) * NCH + wave * 32 + ml * 16 + q * 4] = vv;
        }
#pragma unroll
    for (int off = 32; off > 0; off >>= 1) {
        s1 += __shfl_xor(s1, off);
        s2 += __shfl_xor(s2, off);
    }
    if (lane == 0) { gred[wave * 2 + 0] = s1; gred[wave * 2 + 1] = s2; }
    __syncthreads();
    if (t < 2) {
        float s = gred[t] + gred[2 + t] + gred[4 + t] + gred[6 + t];
        atomicAdd(&((float*)(wsb + GNS_B))[batch * 2 + t], s);
    }
}

// GroupNorm apply; mean/rstd derived inline from the two accumulated scalars.
__global__ __launch_bounds__(256) void k_gnorm(float* __restrict__ out,
                                               const char* __restrict__ wsb,
                                               const float* __restrict__ gw,
                                               const float* __restrict__ gb) {
    size_t base4 = ((size_t)blockIdx.x * 256 + threadIdx.x) * 2;   // float4 index
    int b = (int)(base4 >> 19);
    const float* gns = (const float*)(wsb + GNS_B);
    const float n = (float)NCH * (float)SEQL;
    float mean = gns[b * 2] / n;
    float var = gns[b * 2 + 1] / n - mean * mean;
    float rstd = rsqrtf(var + GEPS);
    int cbase = (int)((base4 & 31) * 4);
    float4 w0 = *(const float4*)&gw[cbase];
    float4 w1 = *(const float4*)&gw[cbase + 4];
    float4 b0 = *(const float4*)&gb[cbase];
    float4 b1 = *(const float4*)&gb[cbase + 4];
    float4 v0 = ((float4*)out)[base4];
    float4 v1 = ((float4*)out)[base4 + 1];
    v0.x = (v0.x - mean) * rstd * w0.x + b0.x;
    v0.y = (v0.y - mean) * rstd * w0.y + b0.y;
    v0.z = (v0.z - mean) * rstd * w0.z + b0.z;
    v0.w = (v0.w - mean) * rstd * w0.w + b0.w;
    v1.x = (v1.x - mean) * rstd * w1.x + b1.x;
    v1.y = (v1.y - mean) * rstd * w1.y + b1.y;
    v1.z = (v1.z - mean) * rstd * w1.z + b1.z;
    v1.w = (v1.w - mean) * rstd * w1.w + b1.w;
    ((float4*)out)[base4] = v0;
    ((float4*)out)[base4 + 1] = v1;
}

extern "C" void kernel_launch(void* const* d_in, const int* in_sizes, int n_in,
                              void* d_out, int out_size, void* d_ws, size_t ws_size,
                              hipStream_t stream) {
    const float* x    = (const float*)d_in[0];
    const float* wqkv = (const float*)d_in[1];
    const float* wout = (const float*)d_in[2];
    const float* bout = (const float*)d_in[3];
    const float* gw   = (const float*)d_in[4];
    const float* gb   = (const float*)d_in[5];
    float* out = (float*)d_out;
    char* wsb  = (char*)d_ws;

    int P = 256;
    while (P > 4 &&
           (size_t)CTXP_B + (size_t)BATCH * P * (16384 + 512) > ws_size)
        P >>= 1;

    k_prep<<<192, 256, 0, stream>>>(wqkv, wout, wsb);
    k_pass1<<<BATCH * P, 256, 0, stream>>>(x, wsb, P);
    k_reduce<<<BATCH * 64, 256, 0, stream>>>(wsb, P);
    k_pass2<<<2048, 256, 0, stream>>>(x, bout, wsb, out);
    k_gnorm<<<8192, 256, 0, stream>>>(out, wsb, gw, gb);
}